// Round 16
// baseline (155.013 us; speedup 1.0000x reference)
//
#include <hip/hip_runtime.h>
#include <hip/hip_bf16.h>

#define LL 768
#define DD 1024
#define DP 128
#define HP 64
#define HH 128
#define NB 64

typedef float f32x4 __attribute__((ext_vector_type(4)));
typedef __bf16 bf16x8 __attribute__((ext_vector_type(8)));
typedef __bf16 bf16x4 __attribute__((ext_vector_type(4)));

// Exact-erf GELU via Abramowitz-Stegun 7.1.26 (abs err <= 1.5e-7), branchless.
__device__ __forceinline__ float gelu_exact(float x) {
    const float z = fabsf(x) * 0.70710678118654752f;
    const float t = __builtin_amdgcn_rcpf(__builtin_fmaf(0.3275911f, z, 1.0f));
    float p = __builtin_fmaf(t, 1.061405429f, -1.453152027f);
    p = __builtin_fmaf(t, p, 1.421413741f);
    p = __builtin_fmaf(t, p, -0.284496736f);
    p = __builtin_fmaf(t, p, 0.254829592f);
    p = p * t;
    const float e = __expf(-z * z);
    const float erfz = __builtin_fmaf(-p, e, 1.0f);
    const float phi = 0.5f * (1.0f + copysignf(erfz, x));
    return x * phi;
}

// ---------------------------------------------------------------------------
// Fused prep + wconv, 200 blocks (R15, proven: non-main 31us -> ~20us).
// ---------------------------------------------------------------------------
__global__ __launch_bounds__(256) void prep_kernel(
    const float* __restrict__ x, const float* __restrict__ Wd,
    const float* __restrict__ bd, const float* __restrict__ W1,
    const float* __restrict__ b1, const float* __restrict__ W2,
    const float* __restrict__ lng, const float* __restrict__ lnb,
    const float* __restrict__ b2,
    __hip_bfloat16* __restrict__ qb, float* __restrict__ kf,
    float* __restrict__ A2, float* __restrict__ Bv,
    __hip_bfloat16* __restrict__ W2gb, float* __restrict__ c2b)
{
    __shared__ __align__(16) float xs[4 * DD];
    __shared__ __align__(16) float xdl[4 * 128];
    const int bid  = blockIdx.x;
    const int tid  = threadIdx.x;
    const int w    = tid >> 6;
    const int lane = tid & 63;

    if (bid >= 192) {                       // ---- wconv role (8 blocks)
        const int nb = bid - 192;
        for (int e = tid; e < 8 * HH; e += 256) {
            const int n = nb * 8 + (e >> 7), h = e & 127;
            W2gb[n * HH + h] = __float2bfloat16(W2[n * HH + h] * lng[h]);
        }
        #pragma unroll
        for (int rr = 0; rr < 2; ++rr) {
            const int n = nb * 8 + w * 2 + rr;
            float s = W2[n * HH + lane] * lnb[lane]
                    + W2[n * HH + 64 + lane] * lnb[64 + lane];
            #pragma unroll
            for (int m = 1; m < 64; m <<= 1) s += __shfl_xor(s, m);
            if (lane == 0) c2b[n] = s + b2[n];
        }
        return;
    }

    // ---- xd role: 4 rows/block, LDS outer-product GEMV
    const int l0 = bid * 4;
    const float4* xg = (const float4*)(x + (size_t)l0 * DD);
    float4* xs4 = (float4*)xs;
    for (int idx = tid; idx < 4 * DD / 4; idx += 256) xs4[idx] = xg[idx];
    __syncthreads();

    const int p = tid & 127;
    const int rg = tid >> 7;
    float acc[2] = {0.f, 0.f};
    #pragma unroll 8
    for (int c = 0; c < DD; c += 4) {
        float4 wv = *(const float4*)(Wd + (size_t)p * DD + c);
        #pragma unroll
        for (int rr = 0; rr < 2; ++rr) {
            float4 xv = *(const float4*)(xs + (rg * 2 + rr) * DD + c);
            acc[rr] += wv.x * xv.x + wv.y * xv.y + wv.z * xv.z + wv.w * xv.w;
        }
    }
    const float bdp = bd[p];
    #pragma unroll
    for (int rr = 0; rr < 2; ++rr) {
        const int row = rg * 2 + rr;
        const float v = acc[rr] + bdp;
        xdl[row * 128 + p] = v;
        if (p < HP) qb[(size_t)(l0 + row) * HP + p] = __float2bfloat16(v);
        else        kf[(size_t)(l0 + row) * HP + (p - HP)] = v;
    }
    __syncthreads();

    const int h = tid & 127;
    const int sel = tid >> 7;
    float a4[4] = {0.f, 0.f, 0.f, 0.f};
    #pragma unroll
    for (int c = 0; c < HP; c += 4) {
        float4 wv = *(const float4*)(W1 + (size_t)h * DP + HP + c);
        #pragma unroll
        for (int r = 0; r < 4; ++r) {
            float4 xv = *(const float4*)(xdl + r * 128 + (sel ? HP : 0) + c);
            a4[r] += wv.x * xv.x + wv.y * xv.y + wv.z * xv.z + wv.w * xv.w;
        }
    }
    if (sel == 0) {
        const float bb = b1[h];
        #pragma unroll
        for (int r = 0; r < 4; ++r)
            A2[(size_t)(l0 + r) * HH + h] = a4[r] + bb;
    } else {
        #pragma unroll
        for (int r = 0; r < 4; ++r)
            Bv[(size_t)(l0 + r) * HH + h] = a4[r];
    }
}

// ---------------------------------------------------------------------------
// Main (R15 values; LDS 49152 -> 32768 for 4 blocks/CU = 16 waves/CU):
//  phase1: Mi[128][64]@0, qt[128][64]@16K         (32K)
//  phase2: hbuf_half[64][128]@0 (over Mi), W2gs[64][128]@16K (over qt)
//  Epilogue+GEMM2 run PER jt HALF; hbuf_half reused for jt=1.
//  W2gs: global loads issued BEFORE bar#2 (T14 split), ds_writes after.
//  bar#3 re-added (cross-wave W2gs dep); jt=1 uses own-rows lgkmcnt trick.
// Registers: 80 arch + 32(acc) + 16(acc2) = 128 -> 4 waves/SIMD; LDS now
// matches (4 blocks x 32K = 128K <= pool). Occupancy 12 -> 16 waves/CU.
// ---------------------------------------------------------------------------
__global__ __launch_bounds__(256, 3) void main_kernel(
    const float* __restrict__ W1, const __hip_bfloat16* __restrict__ W2gb,
    const __hip_bfloat16* __restrict__ qb, const float* __restrict__ kf,
    const float* __restrict__ A2, const float* __restrict__ Bv,
    const float* __restrict__ c2b, float* __restrict__ out)
{
    __shared__ __align__(16) unsigned char smem[32768];
    __bf16* Mi   = (__bf16*)smem;                 // [128][64] swz, phase1
    __bf16* qt   = (__bf16*)(smem + 16384);       // [128][64] swz, phase1
    __bf16* hbuf = (__bf16*)smem;                 // [64][128] swz, phase2
    __bf16* W2gs = (__bf16*)(smem + 16384);       // [64][128] swz, phase2

    const int tid  = threadIdx.x;
    const int lane = tid & 63;
    const int w    = tid >> 6;
    const int lo   = lane & 15;
    const int g4   = lane >> 4;
    const int sw   = (lo & 7) << 3;
    const int i    = blockIdx.y;
    const int j0   = blockIdx.x * 128;

    // ---- stage Mi = bf16(W1a * k_i), swizzled
    {
        const int hrow = tid >> 1;
        const int pb = (tid & 1) * 32;
        const int swr = (hrow & 7) << 3;
        const float* w1r = W1 + (size_t)hrow * DP + pb;
        const float* kfr = kf + (size_t)i * HP + pb;
        #pragma unroll
        for (int m = 0; m < 4; ++m) {
            float4 w0 = *(const float4*)(w1r + m * 8);
            float4 w1v = *(const float4*)(w1r + m * 8 + 4);
            float4 k0 = *(const float4*)(kfr + m * 8);
            float4 k1 = *(const float4*)(kfr + m * 8 + 4);
            bf16x8 t;
            t[0] = (__bf16)(w0.x * k0.x); t[1] = (__bf16)(w0.y * k0.y);
            t[2] = (__bf16)(w0.z * k0.z); t[3] = (__bf16)(w0.w * k0.w);
            t[4] = (__bf16)(w1v.x * k1.x); t[5] = (__bf16)(w1v.y * k1.y);
            t[6] = (__bf16)(w1v.z * k1.z); t[7] = (__bf16)(w1v.w * k1.w);
            *(bf16x8*)&Mi[hrow * 64 + ((pb + m * 8) ^ swr)] = t;
        }
    }
    // ---- stage qt (bf16 bit-copy), swizzled
    {
        const int jl = tid >> 1;
        const int pb = (tid & 1) * 32;
        const int swr = (jl & 7) << 3;
        const unsigned short* src = (const unsigned short*)qb + (size_t)(j0 + jl) * HP + pb;
        #pragma unroll
        for (int m = 0; m < 4; ++m) {
            uint4 v = *(const uint4*)(src + m * 8);
            *(uint4*)&qt[jl * 64 + ((pb + m * 8) ^ swr)] = v;
        }
    }
    __syncthreads();                                    // barrier #1

    // ---- GEMM1 (swapped): acc[jt][ht] = D[h=ht*16+g4*4+r][j=32w+jt*16+lo]
    f32x4 acc[2][8];
    #pragma unroll
    for (int a = 0; a < 2; ++a)
        #pragma unroll
        for (int b = 0; b < 8; ++b)
            #pragma unroll
            for (int e = 0; e < 4; ++e) acc[a][b][e] = 0.f;

    #pragma unroll
    for (int kk = 0; kk < 2; ++kk) {
        const int colx = (kk * 32 + g4 * 8) ^ sw;
        bf16x8 bq[2];
        #pragma unroll
        for (int jt = 0; jt < 2; ++jt)
            bq[jt] = *(const bf16x8*)&qt[(32 * w + jt * 16 + lo) * 64 + colx];
        #pragma unroll
        for (int ht = 0; ht < 8; ++ht) {
            bf16x8 am = *(const bf16x8*)&Mi[(ht * 16 + lo) * 64 + colx];
            #pragma unroll
            for (int jt = 0; jt < 2; ++jt)
                acc[jt][ht] = __builtin_amdgcn_mfma_f32_16x16x32_bf16(am, bq[jt], acc[jt][ht], 0, 0, 0);
        }
    }

    // ---- T14 split: issue W2gs global loads BEFORE the barrier
    uint4 wreg[4];
    {
        const int n = tid >> 2;
        const int hb0 = (tid & 3) * 32;
        const unsigned short* src = (const unsigned short*)W2gb + (size_t)n * HH + hb0;
        #pragma unroll
        for (int m = 0; m < 4; ++m)
            wreg[m] = *(const uint4*)(src + m * 8);
    }
    __syncthreads();                                    // barrier #2 (Mi/qt dead)
    // ---- ds_write W2gs into freed qt region, swizzled
    {
        const int n = tid >> 2;
        const int hb0 = (tid & 3) * 32;
        const int swr = (n & 7) << 3;
        #pragma unroll
        for (int m = 0; m < 4; ++m)
            *(uint4*)&W2gs[n * 128 + ((hb0 + m * 8) ^ swr)] = wreg[m];
    }

    const float* a2base = A2 + (size_t)(j0 + 32 * w + lo) * HH;
    const float* bvr    = Bv + (size_t)i * HH;

    #pragma unroll
    for (int jt = 0; jt < 2; ++jt) {
        // ---- epilogue half: v = acc + A2 - Bv; g = gelu; z=(g-mu)*rstd -> hbuf
        const float* a2r = a2base + (size_t)(jt * 16) * HH;
        float s = 0.f, ss = 0.f;
        #pragma unroll
        for (int ht = 0; ht < 8; ++ht) {
            const int h4 = ht * 16 + g4 * 4;
            f32x4 a2v = *(const f32x4*)&a2r[h4];
            f32x4 bvv = *(const f32x4*)&bvr[h4];
            #pragma unroll
            for (int r = 0; r < 4; ++r) {
                float v = acc[jt][ht][r] + a2v[r] - bvv[r];
                float g = gelu_exact(v);
                acc[jt][ht][r] = g;
                s += g;
                ss = __builtin_fmaf(g, g, ss);
            }
        }
        s  += __shfl_xor(s, 16);  s  += __shfl_xor(s, 32);
        ss += __shfl_xor(ss, 16); ss += __shfl_xor(ss, 32);
        const float mu   = s * (1.0f / 128.0f);
        const float var  = ss * (1.0f / 128.0f) - mu * mu;
        const float rstd = rsqrtf(var + 1e-5f);
        const float nmr  = -mu * rstd;
        const int hrow = w * 16 + lo;            // hbuf_half row (own-wave)
        #pragma unroll
        for (int ht = 0; ht < 8; ++ht) {
            bf16x4 t;
            #pragma unroll
            for (int r = 0; r < 4; ++r)
                t[r] = (__bf16)__builtin_fmaf(acc[jt][ht][r], rstd, nmr);
            *(bf16x4*)&hbuf[hrow * 128 + ((ht * 16 + g4 * 4) ^ sw)] = t;
        }

        if (jt == 0) {
            __syncthreads();                     // barrier #3: W2gs ready (cross-wave)
        } else {
            // own-rows only: in-order LDS pipe + fence vs MFMA hoisting
            asm volatile("s_waitcnt lgkmcnt(0)" ::: "memory");
            __builtin_amdgcn_sched_barrier(0);
        }

        // ---- GEMM2 half: acc2[nt2] = D[n=nt2*16+g4*4+r][j=j0+32w+jt*16+lo]
        f32x4 acc2[4];
        #pragma unroll
        for (int b = 0; b < 4; ++b)
            #pragma unroll
            for (int e = 0; e < 4; ++e) acc2[b][e] = 0.f;

        #pragma unroll
        for (int kk = 0; kk < 4; ++kk) {
            const int colx = (kk * 32 + g4 * 8) ^ sw;
            bf16x8 bh = *(const bf16x8*)&hbuf[(w * 16 + lo) * 128 + colx];
            #pragma unroll
            for (int nt2 = 0; nt2 < 4; ++nt2) {
                bf16x8 aw = *(const bf16x8*)&W2gs[(nt2 * 16 + lo) * 128 + colx];
                acc2[nt2] = __builtin_amdgcn_mfma_f32_16x16x32_bf16(aw, bh, acc2[nt2], 0, 0, 0);
            }
        }

        // ---- store half: out = S + c2b, dwordx4
        const int j = j0 + 32 * w + jt * 16 + lo;
        const size_t base = ((size_t)i * LL + j) * NB;
        #pragma unroll
        for (int nt2 = 0; nt2 < 4; ++nt2) {
            const int n4 = nt2 * 16 + g4 * 4;
            f32x4 c2bv = *(const f32x4*)&c2b[n4];
            f32x4 o;
            #pragma unroll
            for (int r = 0; r < 4; ++r)
                o[r] = acc2[nt2][r] + c2bv[r];
            *(f32x4*)&out[base + n4] = o;
        }

        if (jt == 0) {
            // hbuf_half reuse for jt=1: each wave rewrites ONLY its own rows;
            // own reads (GEMM2 above) already consumed. Cross-wave rows disjoint.
            asm volatile("s_waitcnt lgkmcnt(0)" ::: "memory");
            __builtin_amdgcn_sched_barrier(0);
        }
    }
}

extern "C" void kernel_launch(void* const* d_in, const int* in_sizes, int n_in,
                              void* d_out, int out_size, void* d_ws, size_t ws_size,
                              hipStream_t stream) {
    const float* x   = (const float*)d_in[0];
    const float* Wd  = (const float*)d_in[1];
    const float* bd  = (const float*)d_in[2];
    const float* W1  = (const float*)d_in[3];
    const float* b1  = (const float*)d_in[4];
    const float* lng = (const float*)d_in[5];
    const float* lnb = (const float*)d_in[6];
    const float* W2  = (const float*)d_in[7];
    const float* b2  = (const float*)d_in[8];
    float* out = (float*)d_out;

    char* ws = (char*)d_ws;
    __hip_bfloat16* qb   = (__hip_bfloat16*)ws;              //  98304 B
    float* kf    = (float*)(ws + 98304);                     // 196608 B
    float* A2    = (float*)(ws + 294912);                    // 393216 B [j][h]
    float* Bv    = (float*)(ws + 688128);                    // 393216 B [i][h]
    __hip_bfloat16* W2gb = (__hip_bfloat16*)(ws + 1081344);  //  16384 B
    float* c2b   = (float*)(ws + 1097728);                   //    256 B

    prep_kernel<<<200, 256, 0, stream>>>(x, Wd, bd, W1, b1, W2, lng, lnb, b2,
                                         qb, kf, A2, Bv, W2gb, c2b);
    dim3 grid(6, 768);
    main_kernel<<<grid, 256, 0, stream>>>(W1, W2gb, qb, kf, A2, Bv, c2b, out);
}

// Round 17
// 116.569 us; speedup vs baseline: 1.3298x; 1.3298x over previous
//
#include <hip/hip_runtime.h>
#include <hip/hip_bf16.h>

#define LL 768
#define DD 1024
#define DP 128
#define HP 64
#define HH 128
#define NB 64

typedef float f32x4 __attribute__((ext_vector_type(4)));
typedef __bf16 bf16x8 __attribute__((ext_vector_type(8)));
typedef __bf16 bf16x4 __attribute__((ext_vector_type(4)));

// Exact-erf GELU via Abramowitz-Stegun 7.1.26 (abs err <= 1.5e-7), branchless.
__device__ __forceinline__ float gelu_exact(float x) {
    const float z = fabsf(x) * 0.70710678118654752f;
    const float t = __builtin_amdgcn_rcpf(__builtin_fmaf(0.3275911f, z, 1.0f));
    float p = __builtin_fmaf(t, 1.061405429f, -1.453152027f);
    p = __builtin_fmaf(t, p, 1.421413741f);
    p = __builtin_fmaf(t, p, -0.284496736f);
    p = __builtin_fmaf(t, p, 0.254829592f);
    p = p * t;
    const float e = __expf(-z * z);
    const float erfz = __builtin_fmaf(-p, e, 1.0f);
    const float phi = 0.5f * (1.0f + copysignf(erfz, x));
    return x * phi;
}

// ---------------------------------------------------------------------------
// Fused prep + wconv, 200 blocks (R15 base). NEW: xd-role blocks also emit
// Mig[i][h][p] = bf16(W1a[h][p] * k[i][p]) (12.6 MB) so main_kernel can
// bit-copy Mi instead of recomputing it 6x per i (when ws_size permits).
// ---------------------------------------------------------------------------
template<bool EMIT_MIG>
__global__ __launch_bounds__(256) void prep_kernel(
    const float* __restrict__ x, const float* __restrict__ Wd,
    const float* __restrict__ bd, const float* __restrict__ W1,
    const float* __restrict__ b1, const float* __restrict__ W2,
    const float* __restrict__ lng, const float* __restrict__ lnb,
    const float* __restrict__ b2,
    __hip_bfloat16* __restrict__ qb, float* __restrict__ kf,
    float* __restrict__ A2, float* __restrict__ Bv,
    __hip_bfloat16* __restrict__ W2gb, float* __restrict__ c2b,
    __hip_bfloat16* __restrict__ Mig)
{
    __shared__ __align__(16) float xs[4 * DD];
    __shared__ __align__(16) float xdl[4 * 128];
    const int bid  = blockIdx.x;
    const int tid  = threadIdx.x;
    const int w    = tid >> 6;
    const int lane = tid & 63;

    if (bid >= 192) {                       // ---- wconv role (8 blocks)
        const int nb = bid - 192;
        for (int e = tid; e < 8 * HH; e += 256) {
            const int n = nb * 8 + (e >> 7), h = e & 127;
            W2gb[n * HH + h] = __float2bfloat16(W2[n * HH + h] * lng[h]);
        }
        #pragma unroll
        for (int rr = 0; rr < 2; ++rr) {
            const int n = nb * 8 + w * 2 + rr;
            float s = W2[n * HH + lane] * lnb[lane]
                    + W2[n * HH + 64 + lane] * lnb[64 + lane];
            #pragma unroll
            for (int m = 1; m < 64; m <<= 1) s += __shfl_xor(s, m);
            if (lane == 0) c2b[n] = s + b2[n];
        }
        return;
    }

    // ---- xd role: 4 rows/block, LDS outer-product GEMV
    const int l0 = bid * 4;
    const float4* xg = (const float4*)(x + (size_t)l0 * DD);
    float4* xs4 = (float4*)xs;
    for (int idx = tid; idx < 4 * DD / 4; idx += 256) xs4[idx] = xg[idx];
    __syncthreads();

    const int p = tid & 127;
    const int rg = tid >> 7;
    float acc[2] = {0.f, 0.f};
    #pragma unroll 8
    for (int c = 0; c < DD; c += 4) {
        float4 wv = *(const float4*)(Wd + (size_t)p * DD + c);
        #pragma unroll
        for (int rr = 0; rr < 2; ++rr) {
            float4 xv = *(const float4*)(xs + (rg * 2 + rr) * DD + c);
            acc[rr] += wv.x * xv.x + wv.y * xv.y + wv.z * xv.z + wv.w * xv.w;
        }
    }
    const float bdp = bd[p];
    #pragma unroll
    for (int rr = 0; rr < 2; ++rr) {
        const int row = rg * 2 + rr;
        const float v = acc[rr] + bdp;
        xdl[row * 128 + p] = v;
        if (p < HP) qb[(size_t)(l0 + row) * HP + p] = __float2bfloat16(v);
        else        kf[(size_t)(l0 + row) * HP + (p - HP)] = v;
    }
    __syncthreads();

    // ---- A2 / Bv for the 4 rows
    {
        const int h = tid & 127;
        const int sel = tid >> 7;
        float a4[4] = {0.f, 0.f, 0.f, 0.f};
        #pragma unroll
        for (int c = 0; c < HP; c += 4) {
            float4 wv = *(const float4*)(W1 + (size_t)h * DP + HP + c);
            #pragma unroll
            for (int r = 0; r < 4; ++r) {
                float4 xv = *(const float4*)(xdl + r * 128 + (sel ? HP : 0) + c);
                a4[r] += wv.x * xv.x + wv.y * xv.y + wv.z * xv.z + wv.w * xv.w;
            }
        }
        if (sel == 0) {
            const float bb = b1[h];
            #pragma unroll
            for (int r = 0; r < 4; ++r)
                A2[(size_t)(l0 + r) * HH + h] = a4[r] + bb;
        } else {
            #pragma unroll
            for (int r = 0; r < 4; ++r)
                Bv[(size_t)(l0 + r) * HH + h] = a4[r];
        }
    }

    // ---- Mig[l0+r][h][p] = bf16(W1a[h][p] * k[l0+r][p]) (p<64)
    if (EMIT_MIG) {
        const int po = (tid & 7) * 8;       // p octet
        const int hb = tid >> 3;            // 0..31
        #pragma unroll
        for (int hh = 0; hh < 4; ++hh) {
            const int h = hh * 32 + hb;
            float4 wA = *(const float4*)(W1 + (size_t)h * DP + po);
            float4 wB = *(const float4*)(W1 + (size_t)h * DP + po + 4);
            #pragma unroll
            for (int r = 0; r < 4; ++r) {
                float4 kA = *(const float4*)(xdl + r * 128 + HP + po);
                float4 kB = *(const float4*)(xdl + r * 128 + HP + po + 4);
                bf16x8 t;
                t[0] = (__bf16)(wA.x * kA.x); t[1] = (__bf16)(wA.y * kA.y);
                t[2] = (__bf16)(wA.z * kA.z); t[3] = (__bf16)(wA.w * kA.w);
                t[4] = (__bf16)(wB.x * kB.x); t[5] = (__bf16)(wB.y * kB.y);
                t[6] = (__bf16)(wB.z * kB.z); t[7] = (__bf16)(wB.w * kB.w);
                *(bf16x8*)&Mig[((size_t)(l0 + r) * HH + h) * HP + po] = t;
            }
        }
    }
}

// ---------------------------------------------------------------------------
// Main = R15 (best clean config: 115us, no spill, 3 blocks/CU).
// Template: USE_MIG -> Mi staging is a bit-copy from prep-computed Mig
// (saves ~100 VALU/VMEM insts/thread); else compute in-kernel (R15 path).
// R16 lesson: occupancy is REGISTER-bound (144 regs/wave -> 3 waves/SIMD);
// LDS shrink is void and holding regs across barriers spills. Keep R15 shape.
// ---------------------------------------------------------------------------
template<bool USE_MIG>
__global__ __launch_bounds__(256, 3) void main_kernel(
    const float* __restrict__ W1, const __hip_bfloat16* __restrict__ W2gb,
    const __hip_bfloat16* __restrict__ qb, const float* __restrict__ kf,
    const float* __restrict__ A2, const float* __restrict__ Bv,
    const float* __restrict__ c2b, const __hip_bfloat16* __restrict__ Mig,
    float* __restrict__ out)
{
    __shared__ __align__(16) unsigned char smem[49152];
    __bf16* Mi   = (__bf16*)smem;                 // [128][64] swz
    __bf16* qt   = (__bf16*)(smem + 16384);       // [128][64] swz
    __bf16* W2gs = (__bf16*)(smem + 32768);       // [64][128] swz
    __bf16* hbuf = (__bf16*)smem;                 // [128][128] swz, after bar#2

    const int tid  = threadIdx.x;
    const int lane = tid & 63;
    const int w    = tid >> 6;
    const int lo   = lane & 15;
    const int g4   = lane >> 4;
    const int sw   = (lo & 7) << 3;
    const int i    = blockIdx.y;
    const int j0   = blockIdx.x * 128;

    // ---- stage Mi, swizzled
    if (USE_MIG) {
        const int hrow = tid >> 1;
        const int pb = (tid & 1) * 32;
        const int swr = (hrow & 7) << 3;
        const unsigned short* src = (const unsigned short*)Mig
            + ((size_t)i * HH + hrow) * HP + pb;
        #pragma unroll
        for (int m = 0; m < 4; ++m) {
            uint4 v = *(const uint4*)(src + m * 8);
            *(uint4*)&Mi[hrow * 64 + ((pb + m * 8) ^ swr)] = v;
        }
    } else {
        const int hrow = tid >> 1;
        const int pb = (tid & 1) * 32;
        const int swr = (hrow & 7) << 3;
        const float* w1r = W1 + (size_t)hrow * DP + pb;
        const float* kfr = kf + (size_t)i * HP + pb;
        #pragma unroll
        for (int m = 0; m < 4; ++m) {
            float4 w0 = *(const float4*)(w1r + m * 8);
            float4 w1v = *(const float4*)(w1r + m * 8 + 4);
            float4 k0 = *(const float4*)(kfr + m * 8);
            float4 k1 = *(const float4*)(kfr + m * 8 + 4);
            bf16x8 t;
            t[0] = (__bf16)(w0.x * k0.x); t[1] = (__bf16)(w0.y * k0.y);
            t[2] = (__bf16)(w0.z * k0.z); t[3] = (__bf16)(w0.w * k0.w);
            t[4] = (__bf16)(w1v.x * k1.x); t[5] = (__bf16)(w1v.y * k1.y);
            t[6] = (__bf16)(w1v.z * k1.z); t[7] = (__bf16)(w1v.w * k1.w);
            *(bf16x8*)&Mi[hrow * 64 + ((pb + m * 8) ^ swr)] = t;
        }
    }
    // ---- stage qt (bf16 bit-copy), swizzled
    {
        const int jl = tid >> 1;
        const int pb = (tid & 1) * 32;
        const int swr = (jl & 7) << 3;
        const unsigned short* src = (const unsigned short*)qb + (size_t)(j0 + jl) * HP + pb;
        #pragma unroll
        for (int m = 0; m < 4; ++m) {
            uint4 v = *(const uint4*)(src + m * 8);
            *(uint4*)&qt[jl * 64 + ((pb + m * 8) ^ swr)] = v;
        }
    }
    // ---- stage W2gs (bf16 bit-copy), swizzled
    {
        const int n = tid >> 2;
        const int hb0 = (tid & 3) * 32;
        const int swr = (n & 7) << 3;
        const unsigned short* src = (const unsigned short*)W2gb + (size_t)n * HH + hb0;
        #pragma unroll
        for (int m = 0; m < 4; ++m) {
            uint4 v = *(const uint4*)(src + m * 8);
            *(uint4*)&W2gs[n * 128 + ((hb0 + m * 8) ^ swr)] = v;
        }
    }
    __syncthreads();                                    // barrier #1

    // ---- GEMM1 (swapped): acc[jt][ht] = D[h=ht*16+g4*4+r][j=32w+jt*16+lo]
    f32x4 acc[2][8];
    #pragma unroll
    for (int a = 0; a < 2; ++a)
        #pragma unroll
        for (int b = 0; b < 8; ++b)
            #pragma unroll
            for (int e = 0; e < 4; ++e) acc[a][b][e] = 0.f;

    #pragma unroll
    for (int kk = 0; kk < 2; ++kk) {
        const int colx = (kk * 32 + g4 * 8) ^ sw;
        bf16x8 bq[2];
        #pragma unroll
        for (int jt = 0; jt < 2; ++jt)
            bq[jt] = *(const bf16x8*)&qt[(32 * w + jt * 16 + lo) * 64 + colx];
        #pragma unroll
        for (int ht = 0; ht < 8; ++ht) {
            bf16x8 am = *(const bf16x8*)&Mi[(ht * 16 + lo) * 64 + colx];
            #pragma unroll
            for (int jt = 0; jt < 2; ++jt)
                acc[jt][ht] = __builtin_amdgcn_mfma_f32_16x16x32_bf16(am, bq[jt], acc[jt][ht], 0, 0, 0);
        }
    }

    __syncthreads();                                    // barrier #2 (Mi/qt dead)

    // ---- epilogue: v = acc + A2[j][h] - Bv[i][h]; g = gelu;
    //      z = (g-mu)*rstd -> bf16 -> hbuf (standardize BEFORE rounding)
    #pragma unroll
    for (int jt = 0; jt < 2; ++jt) {
        const int jl = 32 * w + jt * 16 + lo;
        const float* a2r = A2 + (size_t)(j0 + jl) * HH;
        const float* bvr = Bv + (size_t)i * HH;
        float s = 0.f, ss = 0.f;
        #pragma unroll
        for (int ht = 0; ht < 8; ++ht) {
            const int h4 = ht * 16 + g4 * 4;
            f32x4 a2v = *(const f32x4*)&a2r[h4];
            f32x4 bvv = *(const f32x4*)&bvr[h4];
            #pragma unroll
            for (int r = 0; r < 4; ++r) {
                float v = acc[jt][ht][r] + a2v[r] - bvv[r];
                float g = gelu_exact(v);
                acc[jt][ht][r] = g;
                s += g;
                ss = __builtin_fmaf(g, g, ss);
            }
        }
        s  += __shfl_xor(s, 16);  s  += __shfl_xor(s, 32);
        ss += __shfl_xor(ss, 16); ss += __shfl_xor(ss, 32);
        const float mu   = s * (1.0f / 128.0f);
        const float var  = ss * (1.0f / 128.0f) - mu * mu;
        const float rstd = rsqrtf(var + 1e-5f);
        const float nmr  = -mu * rstd;
        #pragma unroll
        for (int ht = 0; ht < 8; ++ht) {
            bf16x4 t;
            #pragma unroll
            for (int r = 0; r < 4; ++r)
                t[r] = (__bf16)__builtin_fmaf(acc[jt][ht][r], rstd, nmr);
            *(bf16x4*)&hbuf[jl * 128 + ((ht * 16 + g4 * 4) ^ sw)] = t;
        }
    }
    // barrier #3 replaced: wave w reads back ONLY its own hbuf rows.
    asm volatile("s_waitcnt lgkmcnt(0)" ::: "memory");
    __builtin_amdgcn_sched_barrier(0);

    // ---- GEMM2 (swapped): acc2[jt][nt2] = D[n=nt2*16+g4*4+r][j=...+lo]
    f32x4 acc2[2][4];
    #pragma unroll
    for (int a = 0; a < 2; ++a)
        #pragma unroll
        for (int b = 0; b < 4; ++b)
            #pragma unroll
            for (int e = 0; e < 4; ++e) acc2[a][b][e] = 0.f;

    #pragma unroll
    for (int kk = 0; kk < 4; ++kk) {
        const int colx = (kk * 32 + g4 * 8) ^ sw;
        bf16x8 bh[2];
        #pragma unroll
        for (int jt = 0; jt < 2; ++jt)
            bh[jt] = *(const bf16x8*)&hbuf[(32 * w + jt * 16 + lo) * 128 + colx];
        #pragma unroll
        for (int nt2 = 0; nt2 < 4; ++nt2) {
            bf16x8 aw = *(const bf16x8*)&W2gs[(nt2 * 16 + lo) * 128 + colx];
            #pragma unroll
            for (int jt = 0; jt < 2; ++jt)
                acc2[jt][nt2] = __builtin_amdgcn_mfma_f32_16x16x32_bf16(aw, bh[jt], acc2[jt][nt2], 0, 0, 0);
        }
    }

    // ---- store: out = S + c2b, dwordx4
    #pragma unroll
    for (int jt = 0; jt < 2; ++jt) {
        const int j = j0 + 32 * w + jt * 16 + lo;
        const size_t base = ((size_t)i * LL + j) * NB;
        #pragma unroll
        for (int nt2 = 0; nt2 < 4; ++nt2) {
            const int n4 = nt2 * 16 + g4 * 4;
            f32x4 c2bv = *(const f32x4*)&c2b[n4];
            f32x4 o;
            #pragma unroll
            for (int r = 0; r < 4; ++r)
                o[r] = acc2[jt][nt2][r] + c2bv[r];
            *(f32x4*)&out[base + n4] = o;
        }
    }
}

extern "C" void kernel_launch(void* const* d_in, const int* in_sizes, int n_in,
                              void* d_out, int out_size, void* d_ws, size_t ws_size,
                              hipStream_t stream) {
    const float* x   = (const float*)d_in[0];
    const float* Wd  = (const float*)d_in[1];
    const float* bd  = (const float*)d_in[2];
    const float* W1  = (const float*)d_in[3];
    const float* b1  = (const float*)d_in[4];
    const float* lng = (const float*)d_in[5];
    const float* lnb = (const float*)d_in[6];
    const float* W2  = (const float*)d_in[7];
    const float* b2  = (const float*)d_in[8];
    float* out = (float*)d_out;

    char* ws = (char*)d_ws;
    __hip_bfloat16* qb   = (__hip_bfloat16*)ws;              //  98304 B
    float* kf    = (float*)(ws + 98304);                     // 196608 B
    float* A2    = (float*)(ws + 294912);                    // 393216 B [j][h]
    float* Bv    = (float*)(ws + 688128);                    // 393216 B [i][h]
    __hip_bfloat16* W2gb = (__hip_bfloat16*)(ws + 1081344);  //  16384 B
    float* c2b   = (float*)(ws + 1097728);                   //    256 B
    __hip_bfloat16* Mig  = (__hip_bfloat16*)(ws + 1097984);  // 12582912 B
    const bool useMig = ws_size >= (size_t)1097984 + 12582912;

    dim3 grid(6, 768);
    if (useMig) {
        prep_kernel<true><<<200, 256, 0, stream>>>(x, Wd, bd, W1, b1, W2, lng,
            lnb, b2, qb, kf, A2, Bv, W2gb, c2b, Mig);
        main_kernel<true><<<grid, 256, 0, stream>>>(W1, W2gb, qb, kf, A2, Bv,
            c2b, Mig, out);
    } else {
        prep_kernel<false><<<200, 256, 0, stream>>>(x, Wd, bd, W1, b1, W2, lng,
            lnb, b2, qb, kf, A2, Bv, W2gb, c2b, Mig);
        main_kernel<false><<<grid, 256, 0, stream>>>(W1, W2gb, qb, kf, A2, Bv,
            c2b, Mig, out);
    }
}

// Round 18
// 112.406 us; speedup vs baseline: 1.3790x; 1.0370x over previous
//
#include <hip/hip_runtime.h>
#include <hip/hip_bf16.h>

#define LL 768
#define DD 1024
#define DP 128
#define HP 64
#define HH 128
#define NB 64

typedef float f32x4 __attribute__((ext_vector_type(4)));
typedef __bf16 bf16x8 __attribute__((ext_vector_type(8)));
typedef __bf16 bf16x4 __attribute__((ext_vector_type(4)));

// Exact-erf GELU via Abramowitz-Stegun 7.1.26 (abs err <= 1.5e-7), branchless.
__device__ __forceinline__ float gelu_exact(float x) {
    const float z = fabsf(x) * 0.70710678118654752f;
    const float t = __builtin_amdgcn_rcpf(__builtin_fmaf(0.3275911f, z, 1.0f));
    float p = __builtin_fmaf(t, 1.061405429f, -1.453152027f);
    p = __builtin_fmaf(t, p, 1.421413741f);
    p = __builtin_fmaf(t, p, -0.284496736f);
    p = __builtin_fmaf(t, p, 0.254829592f);
    p = p * t;
    const float e = __expf(-z * z);
    const float erfz = __builtin_fmaf(-p, e, 1.0f);
    const float phi = 0.5f * (1.0f + copysignf(erfz, x));
    return x * phi;
}

// ---------------------------------------------------------------------------
// Fused prep + wconv, 200 blocks (R17). xd-role blocks also emit
// Mig[i][h][p] = bf16(W1a[h][p] * k[i][p]) so main bit-copies Mi.
// ---------------------------------------------------------------------------
template<bool EMIT_MIG>
__global__ __launch_bounds__(256) void prep_kernel(
    const float* __restrict__ x, const float* __restrict__ Wd,
    const float* __restrict__ bd, const float* __restrict__ W1,
    const float* __restrict__ b1, const float* __restrict__ W2,
    const float* __restrict__ lng, const float* __restrict__ lnb,
    const float* __restrict__ b2,
    __hip_bfloat16* __restrict__ qb, float* __restrict__ kf,
    float* __restrict__ A2, float* __restrict__ Bv,
    __hip_bfloat16* __restrict__ W2gb, float* __restrict__ c2b,
    __hip_bfloat16* __restrict__ Mig)
{
    __shared__ __align__(16) float xs[4 * DD];
    __shared__ __align__(16) float xdl[4 * 128];
    const int bid  = blockIdx.x;
    const int tid  = threadIdx.x;
    const int w    = tid >> 6;
    const int lane = tid & 63;

    if (bid >= 192) {                       // ---- wconv role (8 blocks)
        const int nb = bid - 192;
        for (int e = tid; e < 8 * HH; e += 256) {
            const int n = nb * 8 + (e >> 7), h = e & 127;
            W2gb[n * HH + h] = __float2bfloat16(W2[n * HH + h] * lng[h]);
        }
        #pragma unroll
        for (int rr = 0; rr < 2; ++rr) {
            const int n = nb * 8 + w * 2 + rr;
            float s = W2[n * HH + lane] * lnb[lane]
                    + W2[n * HH + 64 + lane] * lnb[64 + lane];
            #pragma unroll
            for (int m = 1; m < 64; m <<= 1) s += __shfl_xor(s, m);
            if (lane == 0) c2b[n] = s + b2[n];
        }
        return;
    }

    // ---- xd role: 4 rows/block, LDS outer-product GEMV
    const int l0 = bid * 4;
    const float4* xg = (const float4*)(x + (size_t)l0 * DD);
    float4* xs4 = (float4*)xs;
    for (int idx = tid; idx < 4 * DD / 4; idx += 256) xs4[idx] = xg[idx];
    __syncthreads();

    const int p = tid & 127;
    const int rg = tid >> 7;
    float acc[2] = {0.f, 0.f};
    #pragma unroll 8
    for (int c = 0; c < DD; c += 4) {
        float4 wv = *(const float4*)(Wd + (size_t)p * DD + c);
        #pragma unroll
        for (int rr = 0; rr < 2; ++rr) {
            float4 xv = *(const float4*)(xs + (rg * 2 + rr) * DD + c);
            acc[rr] += wv.x * xv.x + wv.y * xv.y + wv.z * xv.z + wv.w * xv.w;
        }
    }
    const float bdp = bd[p];
    #pragma unroll
    for (int rr = 0; rr < 2; ++rr) {
        const int row = rg * 2 + rr;
        const float v = acc[rr] + bdp;
        xdl[row * 128 + p] = v;
        if (p < HP) qb[(size_t)(l0 + row) * HP + p] = __float2bfloat16(v);
        else        kf[(size_t)(l0 + row) * HP + (p - HP)] = v;
    }
    __syncthreads();

    // ---- A2 / Bv for the 4 rows
    {
        const int h = tid & 127;
        const int sel = tid >> 7;
        float a4[4] = {0.f, 0.f, 0.f, 0.f};
        #pragma unroll
        for (int c = 0; c < HP; c += 4) {
            float4 wv = *(const float4*)(W1 + (size_t)h * DP + HP + c);
            #pragma unroll
            for (int r = 0; r < 4; ++r) {
                float4 xv = *(const float4*)(xdl + r * 128 + (sel ? HP : 0) + c);
                a4[r] += wv.x * xv.x + wv.y * xv.y + wv.z * xv.z + wv.w * xv.w;
            }
        }
        if (sel == 0) {
            const float bb = b1[h];
            #pragma unroll
            for (int r = 0; r < 4; ++r)
                A2[(size_t)(l0 + r) * HH + h] = a4[r] + bb;
        } else {
            #pragma unroll
            for (int r = 0; r < 4; ++r)
                Bv[(size_t)(l0 + r) * HH + h] = a4[r];
        }
    }

    // ---- Mig[l0+r][h][p] = bf16(W1a[h][p] * k[l0+r][p]) (p<64)
    if (EMIT_MIG) {
        const int po = (tid & 7) * 8;
        const int hb = tid >> 3;
        #pragma unroll
        for (int hh = 0; hh < 4; ++hh) {
            const int h = hh * 32 + hb;
            float4 wA = *(const float4*)(W1 + (size_t)h * DP + po);
            float4 wB = *(const float4*)(W1 + (size_t)h * DP + po + 4);
            #pragma unroll
            for (int r = 0; r < 4; ++r) {
                float4 kA = *(const float4*)(xdl + r * 128 + HP + po);
                float4 kB = *(const float4*)(xdl + r * 128 + HP + po + 4);
                bf16x8 t;
                t[0] = (__bf16)(wA.x * kA.x); t[1] = (__bf16)(wA.y * kA.y);
                t[2] = (__bf16)(wA.z * kA.z); t[3] = (__bf16)(wA.w * kA.w);
                t[4] = (__bf16)(wB.x * kB.x); t[5] = (__bf16)(wB.y * kB.y);
                t[6] = (__bf16)(wB.z * kB.z); t[7] = (__bf16)(wB.w * kB.w);
                *(bf16x8*)&Mig[((size_t)(l0 + r) * HH + h) * HP + po] = t;
            }
        }
    }
}

// ---------------------------------------------------------------------------
// Main = R17 + XCD-aware 1D grid swizzle (T1):
//   n = blockIdx.x in [0,4608); xcd = n%8; slot = n/8;
//   i = xcd*96 + slot/6 ; j0 = (slot%6)*128.   (bijective: 8*96*6 = 4608)
// All 6 j-tile blocks of one i land on ONE XCD -> Mig/A2 rows become L2-local
// (R17 FETCH 40MB ~ 3x Mig = cross-XCD refetch).
// ---------------------------------------------------------------------------
template<bool USE_MIG>
__global__ __launch_bounds__(256, 3) void main_kernel(
    const float* __restrict__ W1, const __hip_bfloat16* __restrict__ W2gb,
    const __hip_bfloat16* __restrict__ qb, const float* __restrict__ kf,
    const float* __restrict__ A2, const float* __restrict__ Bv,
    const float* __restrict__ c2b, const __hip_bfloat16* __restrict__ Mig,
    float* __restrict__ out)
{
    __shared__ __align__(16) unsigned char smem[49152];
    __bf16* Mi   = (__bf16*)smem;                 // [128][64] swz
    __bf16* qt   = (__bf16*)(smem + 16384);       // [128][64] swz
    __bf16* W2gs = (__bf16*)(smem + 32768);       // [64][128] swz
    __bf16* hbuf = (__bf16*)smem;                 // [128][128] swz, after bar#2

    const int tid  = threadIdx.x;
    const int lane = tid & 63;
    const int w    = tid >> 6;
    const int lo   = lane & 15;
    const int g4   = lane >> 4;
    const int sw   = (lo & 7) << 3;
    const int n    = blockIdx.x;
    const int xcd  = n & 7;
    const int slot = n >> 3;
    const int i    = xcd * 96 + slot / 6;
    const int j0   = (slot % 6) * 128;

    // ---- stage Mi, swizzled
    if (USE_MIG) {
        const int hrow = tid >> 1;
        const int pb = (tid & 1) * 32;
        const int swr = (hrow & 7) << 3;
        const unsigned short* src = (const unsigned short*)Mig
            + ((size_t)i * HH + hrow) * HP + pb;
        #pragma unroll
        for (int m = 0; m < 4; ++m) {
            uint4 v = *(const uint4*)(src + m * 8);
            *(uint4*)&Mi[hrow * 64 + ((pb + m * 8) ^ swr)] = v;
        }
    } else {
        const int hrow = tid >> 1;
        const int pb = (tid & 1) * 32;
        const int swr = (hrow & 7) << 3;
        const float* w1r = W1 + (size_t)hrow * DP + pb;
        const float* kfr = kf + (size_t)i * HP + pb;
        #pragma unroll
        for (int m = 0; m < 4; ++m) {
            float4 w0 = *(const float4*)(w1r + m * 8);
            float4 w1v = *(const float4*)(w1r + m * 8 + 4);
            float4 k0 = *(const float4*)(kfr + m * 8);
            float4 k1 = *(const float4*)(kfr + m * 8 + 4);
            bf16x8 t;
            t[0] = (__bf16)(w0.x * k0.x); t[1] = (__bf16)(w0.y * k0.y);
            t[2] = (__bf16)(w0.z * k0.z); t[3] = (__bf16)(w0.w * k0.w);
            t[4] = (__bf16)(w1v.x * k1.x); t[5] = (__bf16)(w1v.y * k1.y);
            t[6] = (__bf16)(w1v.z * k1.z); t[7] = (__bf16)(w1v.w * k1.w);
            *(bf16x8*)&Mi[hrow * 64 + ((pb + m * 8) ^ swr)] = t;
        }
    }
    // ---- stage qt (bf16 bit-copy), swizzled
    {
        const int jl = tid >> 1;
        const int pb = (tid & 1) * 32;
        const int swr = (jl & 7) << 3;
        const unsigned short* src = (const unsigned short*)qb + (size_t)(j0 + jl) * HP + pb;
        #pragma unroll
        for (int m = 0; m < 4; ++m) {
            uint4 v = *(const uint4*)(src + m * 8);
            *(uint4*)&qt[jl * 64 + ((pb + m * 8) ^ swr)] = v;
        }
    }
    // ---- stage W2gs (bf16 bit-copy), swizzled
    {
        const int nn = tid >> 2;
        const int hb0 = (tid & 3) * 32;
        const int swr = (nn & 7) << 3;
        const unsigned short* src = (const unsigned short*)W2gb + (size_t)nn * HH + hb0;
        #pragma unroll
        for (int m = 0; m < 4; ++m) {
            uint4 v = *(const uint4*)(src + m * 8);
            *(uint4*)&W2gs[nn * 128 + ((hb0 + m * 8) ^ swr)] = v;
        }
    }
    __syncthreads();                                    // barrier #1

    // ---- GEMM1 (swapped): acc[jt][ht] = D[h=ht*16+g4*4+r][j=32w+jt*16+lo]
    f32x4 acc[2][8];
    #pragma unroll
    for (int a = 0; a < 2; ++a)
        #pragma unroll
        for (int b = 0; b < 8; ++b)
            #pragma unroll
            for (int e = 0; e < 4; ++e) acc[a][b][e] = 0.f;

    #pragma unroll
    for (int kk = 0; kk < 2; ++kk) {
        const int colx = (kk * 32 + g4 * 8) ^ sw;
        bf16x8 bq[2];
        #pragma unroll
        for (int jt = 0; jt < 2; ++jt)
            bq[jt] = *(const bf16x8*)&qt[(32 * w + jt * 16 + lo) * 64 + colx];
        #pragma unroll
        for (int ht = 0; ht < 8; ++ht) {
            bf16x8 am = *(const bf16x8*)&Mi[(ht * 16 + lo) * 64 + colx];
            #pragma unroll
            for (int jt = 0; jt < 2; ++jt)
                acc[jt][ht] = __builtin_amdgcn_mfma_f32_16x16x32_bf16(am, bq[jt], acc[jt][ht], 0, 0, 0);
        }
    }

    __syncthreads();                                    // barrier #2 (Mi/qt dead)

    // ---- epilogue: v = acc + A2[j][h] - Bv[i][h]; g = gelu;
    //      z = (g-mu)*rstd -> bf16 -> hbuf (standardize BEFORE rounding)
    #pragma unroll
    for (int jt = 0; jt < 2; ++jt) {
        const int jl = 32 * w + jt * 16 + lo;
        const float* a2r = A2 + (size_t)(j0 + jl) * HH;
        const float* bvr = Bv + (size_t)i * HH;
        float s = 0.f, ss = 0.f;
        #pragma unroll
        for (int ht = 0; ht < 8; ++ht) {
            const int h4 = ht * 16 + g4 * 4;
            f32x4 a2v = *(const f32x4*)&a2r[h4];
            f32x4 bvv = *(const f32x4*)&bvr[h4];
            #pragma unroll
            for (int r = 0; r < 4; ++r) {
                float v = acc[jt][ht][r] + a2v[r] - bvv[r];
                float g = gelu_exact(v);
                acc[jt][ht][r] = g;
                s += g;
                ss = __builtin_fmaf(g, g, ss);
            }
        }
        s  += __shfl_xor(s, 16);  s  += __shfl_xor(s, 32);
        ss += __shfl_xor(ss, 16); ss += __shfl_xor(ss, 32);
        const float mu   = s * (1.0f / 128.0f);
        const float var  = ss * (1.0f / 128.0f) - mu * mu;
        const float rstd = rsqrtf(var + 1e-5f);
        const float nmr  = -mu * rstd;
        #pragma unroll
        for (int ht = 0; ht < 8; ++ht) {
            bf16x4 t;
            #pragma unroll
            for (int r = 0; r < 4; ++r)
                t[r] = (__bf16)__builtin_fmaf(acc[jt][ht][r], rstd, nmr);
            *(bf16x4*)&hbuf[jl * 128 + ((ht * 16 + g4 * 4) ^ sw)] = t;
        }
    }
    // barrier #3 replaced: wave w reads back ONLY its own hbuf rows.
    asm volatile("s_waitcnt lgkmcnt(0)" ::: "memory");
    __builtin_amdgcn_sched_barrier(0);

    // ---- GEMM2 (swapped): acc2[jt][nt2] = D[n=nt2*16+g4*4+r][j=...+lo]
    f32x4 acc2[2][4];
    #pragma unroll
    for (int a = 0; a < 2; ++a)
        #pragma unroll
        for (int b = 0; b < 4; ++b)
            #pragma unroll
            for (int e = 0; e < 4; ++e) acc2[a][b][e] = 0.f;

    #pragma unroll
    for (int kk = 0; kk < 4; ++kk) {
        const int colx = (kk * 32 + g4 * 8) ^ sw;
        bf16x8 bh[2];
        #pragma unroll
        for (int jt = 0; jt < 2; ++jt)
            bh[jt] = *(const bf16x8*)&hbuf[(32 * w + jt * 16 + lo) * 128 + colx];
        #pragma unroll
        for (int nt2 = 0; nt2 < 4; ++nt2) {
            bf16x8 aw = *(const bf16x8*)&W2gs[(nt2 * 16 + lo) * 128 + colx];
            #pragma unroll
            for (int jt = 0; jt < 2; ++jt)
                acc2[jt][nt2] = __builtin_amdgcn_mfma_f32_16x16x32_bf16(aw, bh[jt], acc2[jt][nt2], 0, 0, 0);
        }
    }

    // ---- store: out = S + c2b, dwordx4
    #pragma unroll
    for (int jt = 0; jt < 2; ++jt) {
        const int j = j0 + 32 * w + jt * 16 + lo;
        const size_t base = ((size_t)i * LL + j) * NB;
        #pragma unroll
        for (int nt2 = 0; nt2 < 4; ++nt2) {
            const int n4 = nt2 * 16 + g4 * 4;
            f32x4 c2bv = *(const f32x4*)&c2b[n4];
            f32x4 o;
            #pragma unroll
            for (int r = 0; r < 4; ++r)
                o[r] = acc2[jt][nt2][r] + c2bv[r];
            *(f32x4*)&out[base + n4] = o;
        }
    }
}

extern "C" void kernel_launch(void* const* d_in, const int* in_sizes, int n_in,
                              void* d_out, int out_size, void* d_ws, size_t ws_size,
                              hipStream_t stream) {
    const float* x   = (const float*)d_in[0];
    const float* Wd  = (const float*)d_in[1];
    const float* bd  = (const float*)d_in[2];
    const float* W1  = (const float*)d_in[3];
    const float* b1  = (const float*)d_in[4];
    const float* lng = (const float*)d_in[5];
    const float* lnb = (const float*)d_in[6];
    const float* W2  = (const float*)d_in[7];
    const float* b2  = (const float*)d_in[8];
    float* out = (float*)d_out;

    char* ws = (char*)d_ws;
    __hip_bfloat16* qb   = (__hip_bfloat16*)ws;              //  98304 B
    float* kf    = (float*)(ws + 98304);                     // 196608 B
    float* A2    = (float*)(ws + 294912);                    // 393216 B [j][h]
    float* Bv    = (float*)(ws + 688128);                    // 393216 B [i][h]
    __hip_bfloat16* W2gb = (__hip_bfloat16*)(ws + 1081344);  //  16384 B
    float* c2b   = (float*)(ws + 1097728);                   //    256 B
    __hip_bfloat16* Mig  = (__hip_bfloat16*)(ws + 1097984);  // 12582912 B
    const bool useMig = ws_size >= (size_t)1097984 + 12582912;

    if (useMig) {
        prep_kernel<true><<<200, 256, 0, stream>>>(x, Wd, bd, W1, b1, W2, lng,
            lnb, b2, qb, kf, A2, Bv, W2gb, c2b, Mig);
        main_kernel<true><<<4608, 256, 0, stream>>>(W1, W2gb, qb, kf, A2, Bv,
            c2b, Mig, out);
    } else {
        prep_kernel<false><<<200, 256, 0, stream>>>(x, Wd, bd, W1, b1, W2, lng,
            lnb, b2, qb, kf, A2, Bv, W2gb, c2b, Mig);
        main_kernel<false><<<4608, 256, 0, stream>>>(W1, W2gb, qb, kf, A2, Bv,
            c2b, Mig, out);
    }
}

// Round 19
// 109.582 us; speedup vs baseline: 1.4146x; 1.0258x over previous
//
#include <hip/hip_runtime.h>
#include <hip/hip_bf16.h>

#define LL 768
#define DD 1024
#define DP 128
#define HP 64
#define HH 128
#define NB 64

typedef float f32x4 __attribute__((ext_vector_type(4)));
typedef __bf16 bf16x8 __attribute__((ext_vector_type(8)));
typedef __bf16 bf16x4 __attribute__((ext_vector_type(4)));

// async global->LDS, 16B/lane, LDS dest = wave-uniform base + lane*16 (linear)
#define GLOAD_LDS16(g, l) __builtin_amdgcn_global_load_lds( \
    (const __attribute__((address_space(1))) void*)(g), \
    (__attribute__((address_space(3))) void*)(l), 16, 0, 0)

// Exact-erf GELU via Abramowitz-Stegun 7.1.26 (abs err <= 1.5e-7), branchless.
__device__ __forceinline__ float gelu_exact(float x) {
    const float z = fabsf(x) * 0.70710678118654752f;
    const float t = __builtin_amdgcn_rcpf(__builtin_fmaf(0.3275911f, z, 1.0f));
    float p = __builtin_fmaf(t, 1.061405429f, -1.453152027f);
    p = __builtin_fmaf(t, p, 1.421413741f);
    p = __builtin_fmaf(t, p, -0.284496736f);
    p = __builtin_fmaf(t, p, 0.254829592f);
    p = p * t;
    const float e = __expf(-z * z);
    const float erfz = __builtin_fmaf(-p, e, 1.0f);
    const float phi = 0.5f * (1.0f + copysignf(erfz, x));
    return x * phi;
}

// ---------------------------------------------------------------------------
// Fused prep + wconv, 200 blocks (R18 unchanged).
// ---------------------------------------------------------------------------
template<bool EMIT_MIG>
__global__ __launch_bounds__(256) void prep_kernel(
    const float* __restrict__ x, const float* __restrict__ Wd,
    const float* __restrict__ bd, const float* __restrict__ W1,
    const float* __restrict__ b1, const float* __restrict__ W2,
    const float* __restrict__ lng, const float* __restrict__ lnb,
    const float* __restrict__ b2,
    __hip_bfloat16* __restrict__ qb, float* __restrict__ kf,
    float* __restrict__ A2, float* __restrict__ Bv,
    __hip_bfloat16* __restrict__ W2gb, float* __restrict__ c2b,
    __hip_bfloat16* __restrict__ Mig)
{
    __shared__ __align__(16) float xs[4 * DD];
    __shared__ __align__(16) float xdl[4 * 128];
    const int bid  = blockIdx.x;
    const int tid  = threadIdx.x;
    const int w    = tid >> 6;
    const int lane = tid & 63;

    if (bid >= 192) {                       // ---- wconv role (8 blocks)
        const int nb = bid - 192;
        for (int e = tid; e < 8 * HH; e += 256) {
            const int n = nb * 8 + (e >> 7), h = e & 127;
            W2gb[n * HH + h] = __float2bfloat16(W2[n * HH + h] * lng[h]);
        }
        #pragma unroll
        for (int rr = 0; rr < 2; ++rr) {
            const int n = nb * 8 + w * 2 + rr;
            float s = W2[n * HH + lane] * lnb[lane]
                    + W2[n * HH + 64 + lane] * lnb[64 + lane];
            #pragma unroll
            for (int m = 1; m < 64; m <<= 1) s += __shfl_xor(s, m);
            if (lane == 0) c2b[n] = s + b2[n];
        }
        return;
    }

    // ---- xd role: 4 rows/block, LDS outer-product GEMV
    const int l0 = bid * 4;
    const float4* xg = (const float4*)(x + (size_t)l0 * DD);
    float4* xs4 = (float4*)xs;
    for (int idx = tid; idx < 4 * DD / 4; idx += 256) xs4[idx] = xg[idx];
    __syncthreads();

    const int p = tid & 127;
    const int rg = tid >> 7;
    float acc[2] = {0.f, 0.f};
    #pragma unroll 8
    for (int c = 0; c < DD; c += 4) {
        float4 wv = *(const float4*)(Wd + (size_t)p * DD + c);
        #pragma unroll
        for (int rr = 0; rr < 2; ++rr) {
            float4 xv = *(const float4*)(xs + (rg * 2 + rr) * DD + c);
            acc[rr] += wv.x * xv.x + wv.y * xv.y + wv.z * xv.z + wv.w * xv.w;
        }
    }
    const float bdp = bd[p];
    #pragma unroll
    for (int rr = 0; rr < 2; ++rr) {
        const int row = rg * 2 + rr;
        const float v = acc[rr] + bdp;
        xdl[row * 128 + p] = v;
        if (p < HP) qb[(size_t)(l0 + row) * HP + p] = __float2bfloat16(v);
        else        kf[(size_t)(l0 + row) * HP + (p - HP)] = v;
    }
    __syncthreads();

    // ---- A2 / Bv for the 4 rows
    {
        const int h = tid & 127;
        const int sel = tid >> 7;
        float a4[4] = {0.f, 0.f, 0.f, 0.f};
        #pragma unroll
        for (int c = 0; c < HP; c += 4) {
            float4 wv = *(const float4*)(W1 + (size_t)h * DP + HP + c);
            #pragma unroll
            for (int r = 0; r < 4; ++r) {
                float4 xv = *(const float4*)(xdl + r * 128 + (sel ? HP : 0) + c);
                a4[r] += wv.x * xv.x + wv.y * xv.y + wv.z * xv.z + wv.w * xv.w;
            }
        }
        if (sel == 0) {
            const float bb = b1[h];
            #pragma unroll
            for (int r = 0; r < 4; ++r)
                A2[(size_t)(l0 + r) * HH + h] = a4[r] + bb;
        } else {
            #pragma unroll
            for (int r = 0; r < 4; ++r)
                Bv[(size_t)(l0 + r) * HH + h] = a4[r];
        }
    }

    // ---- Mig[l0+r][h][p] = bf16(W1a[h][p] * k[l0+r][p]) (p<64)
    if (EMIT_MIG) {
        const int po = (tid & 7) * 8;
        const int hb = tid >> 3;
        #pragma unroll
        for (int hh = 0; hh < 4; ++hh) {
            const int h = hh * 32 + hb;
            float4 wA = *(const float4*)(W1 + (size_t)h * DP + po);
            float4 wB = *(const float4*)(W1 + (size_t)h * DP + po + 4);
            #pragma unroll
            for (int r = 0; r < 4; ++r) {
                float4 kA = *(const float4*)(xdl + r * 128 + HP + po);
                float4 kB = *(const float4*)(xdl + r * 128 + HP + po + 4);
                bf16x8 t;
                t[0] = (__bf16)(wA.x * kA.x); t[1] = (__bf16)(wA.y * kA.y);
                t[2] = (__bf16)(wA.z * kA.z); t[3] = (__bf16)(wA.w * kA.w);
                t[4] = (__bf16)(wB.x * kB.x); t[5] = (__bf16)(wB.y * kB.y);
                t[6] = (__bf16)(wB.z * kB.z); t[7] = (__bf16)(wB.w * kB.w);
                *(bf16x8*)&Mig[((size_t)(l0 + r) * HH + h) * HP + po] = t;
            }
        }
    }
}

// ---------------------------------------------------------------------------
// Main = R18 + global_load_lds staging (rule-21: linear LDS dest +
// inverse-swizzled GLOBAL source + swizzled reads; XOR involution ->
// reads fetch bit-identical data). 12 wave-level staging insts replace
// ~24 per-thread load/ds_write ops + VGPR wait chains on the barrier-#1
// critical path (R17 proved staging-path cuts pay ~10x).
// ---------------------------------------------------------------------------
template<bool USE_MIG>
__global__ __launch_bounds__(256, 3) void main_kernel(
    const float* __restrict__ W1, const __hip_bfloat16* __restrict__ W2gb,
    const __hip_bfloat16* __restrict__ qb, const float* __restrict__ kf,
    const float* __restrict__ A2, const float* __restrict__ Bv,
    const float* __restrict__ c2b, const __hip_bfloat16* __restrict__ Mig,
    float* __restrict__ out)
{
    __shared__ __align__(16) unsigned char smem[49152];
    __bf16* Mi   = (__bf16*)smem;                 // [128][64] swz
    __bf16* qt   = (__bf16*)(smem + 16384);       // [128][64] swz
    __bf16* W2gs = (__bf16*)(smem + 32768);       // [64][128] swz
    __bf16* hbuf = (__bf16*)smem;                 // [128][128] swz, after bar#2

    const int tid  = threadIdx.x;
    const int lane = tid & 63;
    const int w    = tid >> 6;
    const int lo   = lane & 15;
    const int g4   = lane >> 4;
    const int sw   = (lo & 7) << 3;
    const int n    = blockIdx.x;
    const int xcd  = n & 7;
    const int slot = n >> 3;
    const int i    = xcd * 96 + slot / 6;
    const int j0   = (slot % 6) * 128;

    // ---- stage Mi (rows 128, 128B each; wave w -> rows [32w,32w+32) linear)
    if (USE_MIG) {
        const char* migb = (const char*)Mig + (size_t)i * HH * HP * 2;
        #pragma unroll
        for (int c = 0; c < 4; ++c) {
            const int row = w * 32 + c * 8 + (lane >> 3);
            const int bc  = (lane & 7) * 16;
            const char* src = migb + row * 128 + (bc ^ ((row & 7) << 4));
            GLOAD_LDS16(src, (char*)Mi + w * 4096 + c * 1024);
        }
    } else {
        const int hrow = tid >> 1;
        const int pb = (tid & 1) * 32;
        const int swr = (hrow & 7) << 3;
        const float* w1r = W1 + (size_t)hrow * DP + pb;
        const float* kfr = kf + (size_t)i * HP + pb;
        #pragma unroll
        for (int m = 0; m < 4; ++m) {
            float4 w0 = *(const float4*)(w1r + m * 8);
            float4 w1v = *(const float4*)(w1r + m * 8 + 4);
            float4 k0 = *(const float4*)(kfr + m * 8);
            float4 k1 = *(const float4*)(kfr + m * 8 + 4);
            bf16x8 t;
            t[0] = (__bf16)(w0.x * k0.x); t[1] = (__bf16)(w0.y * k0.y);
            t[2] = (__bf16)(w0.z * k0.z); t[3] = (__bf16)(w0.w * k0.w);
            t[4] = (__bf16)(w1v.x * k1.x); t[5] = (__bf16)(w1v.y * k1.y);
            t[6] = (__bf16)(w1v.z * k1.z); t[7] = (__bf16)(w1v.w * k1.w);
            *(bf16x8*)&Mi[hrow * 64 + ((pb + m * 8) ^ swr)] = t;
        }
    }
    // ---- stage qt (same geometry as Mi, source qb rows j0+row)
    {
        const char* qbb = (const char*)qb + (size_t)j0 * HP * 2;
        #pragma unroll
        for (int c = 0; c < 4; ++c) {
            const int row = w * 32 + c * 8 + (lane >> 3);
            const int bc  = (lane & 7) * 16;
            const char* src = qbb + row * 128 + (bc ^ ((row & 7) << 4));
            GLOAD_LDS16(src, (char*)qt + w * 4096 + c * 1024);
        }
    }
    // ---- stage W2gs (64 rows, 256B each; wave w -> rows [16w,16w+16) linear)
    {
        const char* w2b = (const char*)W2gb;
        #pragma unroll
        for (int c = 0; c < 4; ++c) {
            const int row = w * 16 + c * 4 + (lane >> 4);
            const int bc  = (lane & 15) * 16;
            const char* src = w2b + row * 256 + (bc ^ ((row & 7) << 4));
            GLOAD_LDS16(src, (char*)W2gs + w * 4096 + c * 1024);
        }
    }
    __syncthreads();                                    // barrier #1 (drains vmcnt)

    // ---- GEMM1 (swapped): acc[jt][ht] = D[h=ht*16+g4*4+r][j=32w+jt*16+lo]
    f32x4 acc[2][8];
    #pragma unroll
    for (int a = 0; a < 2; ++a)
        #pragma unroll
        for (int b = 0; b < 8; ++b)
            #pragma unroll
            for (int e = 0; e < 4; ++e) acc[a][b][e] = 0.f;

    #pragma unroll
    for (int kk = 0; kk < 2; ++kk) {
        const int colx = (kk * 32 + g4 * 8) ^ sw;
        bf16x8 bq[2];
        #pragma unroll
        for (int jt = 0; jt < 2; ++jt)
            bq[jt] = *(const bf16x8*)&qt[(32 * w + jt * 16 + lo) * 64 + colx];
        #pragma unroll
        for (int ht = 0; ht < 8; ++ht) {
            bf16x8 am = *(const bf16x8*)&Mi[(ht * 16 + lo) * 64 + colx];
            #pragma unroll
            for (int jt = 0; jt < 2; ++jt)
                acc[jt][ht] = __builtin_amdgcn_mfma_f32_16x16x32_bf16(am, bq[jt], acc[jt][ht], 0, 0, 0);
        }
    }

    __syncthreads();                                    // barrier #2 (Mi/qt dead)

    // ---- epilogue: v = acc + A2[j][h] - Bv[i][h]; g = gelu;
    //      z = (g-mu)*rstd -> bf16 -> hbuf (standardize BEFORE rounding)
    #pragma unroll
    for (int jt = 0; jt < 2; ++jt) {
        const int jl = 32 * w + jt * 16 + lo;
        const float* a2r = A2 + (size_t)(j0 + jl) * HH;
        const float* bvr = Bv + (size_t)i * HH;
        float s = 0.f, ss = 0.f;
        #pragma unroll
        for (int ht = 0; ht < 8; ++ht) {
            const int h4 = ht * 16 + g4 * 4;
            f32x4 a2v = *(const f32x4*)&a2r[h4];
            f32x4 bvv = *(const f32x4*)&bvr[h4];
            #pragma unroll
            for (int r = 0; r < 4; ++r) {
                float v = acc[jt][ht][r] + a2v[r] - bvv[r];
                float g = gelu_exact(v);
                acc[jt][ht][r] = g;
                s += g;
                ss = __builtin_fmaf(g, g, ss);
            }
        }
        s  += __shfl_xor(s, 16);  s  += __shfl_xor(s, 32);
        ss += __shfl_xor(ss, 16); ss += __shfl_xor(ss, 32);
        const float mu   = s * (1.0f / 128.0f);
        const float var  = ss * (1.0f / 128.0f) - mu * mu;
        const float rstd = rsqrtf(var + 1e-5f);
        const float nmr  = -mu * rstd;
        #pragma unroll
        for (int ht = 0; ht < 8; ++ht) {
            bf16x4 t;
            #pragma unroll
            for (int r = 0; r < 4; ++r)
                t[r] = (__bf16)__builtin_fmaf(acc[jt][ht][r], rstd, nmr);
            *(bf16x4*)&hbuf[jl * 128 + ((ht * 16 + g4 * 4) ^ sw)] = t;
        }
    }
    // barrier #3 replaced: wave w reads back ONLY its own hbuf rows.
    asm volatile("s_waitcnt lgkmcnt(0)" ::: "memory");
    __builtin_amdgcn_sched_barrier(0);

    // ---- GEMM2 (swapped): acc2[jt][nt2] = D[n=nt2*16+g4*4+r][j=...+lo]
    f32x4 acc2[2][4];
    #pragma unroll
    for (int a = 0; a < 2; ++a)
        #pragma unroll
        for (int b = 0; b < 4; ++b)
            #pragma unroll
            for (int e = 0; e < 4; ++e) acc2[a][b][e] = 0.f;

    #pragma unroll
    for (int kk = 0; kk < 4; ++kk) {
        const int colx = (kk * 32 + g4 * 8) ^ sw;
        bf16x8 bh[2];
        #pragma unroll
        for (int jt = 0; jt < 2; ++jt)
            bh[jt] = *(const bf16x8*)&hbuf[(32 * w + jt * 16 + lo) * 128 + colx];
        #pragma unroll
        for (int nt2 = 0; nt2 < 4; ++nt2) {
            bf16x8 aw = *(const bf16x8*)&W2gs[(nt2 * 16 + lo) * 128 + colx];
            #pragma unroll
            for (int jt = 0; jt < 2; ++jt)
                acc2[jt][nt2] = __builtin_amdgcn_mfma_f32_16x16x32_bf16(aw, bh[jt], acc2[jt][nt2], 0, 0, 0);
        }
    }

    // ---- store: out = S + c2b, dwordx4
    #pragma unroll
    for (int jt = 0; jt < 2; ++jt) {
        const int j = j0 + 32 * w + jt * 16 + lo;
        const size_t base = ((size_t)i * LL + j) * NB;
        #pragma unroll
        for (int nt2 = 0; nt2 < 4; ++nt2) {
            const int n4 = nt2 * 16 + g4 * 4;
            f32x4 c2bv = *(const f32x4*)&c2b[n4];
            f32x4 o;
            #pragma unroll
            for (int r = 0; r < 4; ++r)
                o[r] = acc2[jt][nt2][r] + c2bv[r];
            *(f32x4*)&out[base + n4] = o;
        }
    }
}

extern "C" void kernel_launch(void* const* d_in, const int* in_sizes, int n_in,
                              void* d_out, int out_size, void* d_ws, size_t ws_size,
                              hipStream_t stream) {
    const float* x   = (const float*)d_in[0];
    const float* Wd  = (const float*)d_in[1];
    const float* bd  = (const float*)d_in[2];
    const float* W1  = (const float*)d_in[3];
    const float* b1  = (const float*)d_in[4];
    const float* lng = (const float*)d_in[5];
    const float* lnb = (const float*)d_in[6];
    const float* W2  = (const float*)d_in[7];
    const float* b2  = (const float*)d_in[8];
    float* out = (float*)d_out;

    char* ws = (char*)d_ws;
    __hip_bfloat16* qb   = (__hip_bfloat16*)ws;              //  98304 B
    float* kf    = (float*)(ws + 98304);                     // 196608 B
    float* A2    = (float*)(ws + 294912);                    // 393216 B [j][h]
    float* Bv    = (float*)(ws + 688128);                    // 393216 B [i][h]
    __hip_bfloat16* W2gb = (__hip_bfloat16*)(ws + 1081344);  //  16384 B
    float* c2b   = (float*)(ws + 1097728);                   //    256 B
    __hip_bfloat16* Mig  = (__hip_bfloat16*)(ws + 1097984);  // 12582912 B
    const bool useMig = ws_size >= (size_t)1097984 + 12582912;

    if (useMig) {
        prep_kernel<true><<<200, 256, 0, stream>>>(x, Wd, bd, W1, b1, W2, lng,
            lnb, b2, qb, kf, A2, Bv, W2gb, c2b, Mig);
        main_kernel<true><<<4608, 256, 0, stream>>>(W1, W2gb, qb, kf, A2, Bv,
            c2b, Mig, out);
    } else {
        prep_kernel<false><<<200, 256, 0, stream>>>(x, Wd, bd, W1, b1, W2, lng,
            lnb, b2, qb, kf, A2, Bv, W2gb, c2b, Mig);
        main_kernel<false><<<4608, 256, 0, stream>>>(W1, W2gb, qb, kf, A2, Bv,
            c2b, Mig, out);
    }
}